// Round 5
// baseline (54.874 us; speedup 1.0000x reference)
//
#include <hip/hip_runtime.h>

// CTC batch loss forward (Keras ctc_batch_cost semantics).
// B=2048, T=256, L=32, V=128, blank=V-1=127, S=2L+1=65.
// One wave64 per batch item: lane s owns state s (0..63); lane 0 also owns
// state 64 (final blank, shares lane 0's blank log-prob).
// alpha in streaming-softmax form: alpha2 = m + log2(p) (base-2);
// m-recurrence = shfl -> max3 -> add (no transcendental on the chain),
// p folded into m every 8 steps.
// Memory: coalesced float2 row loads (lane l -> cols 2l,2l+1) + fixed
// ds_bpermute redistribution (lane -> its sym column), PF=16 ring.

constexpr int Bb = 2048;
constexpr int Tt = 256;
constexpr int Ll = 32;
constexpr int Vv = 128;
constexpr int BLANK = Vv - 1;
constexpr int PF = 16;
#define EPSF 1e-7f
#define NEGF -1e30f
#define LN2F 0.6931471805599453f

__device__ __forceinline__ float fexp2(float x) { return __builtin_amdgcn_exp2f(x); }
__device__ __forceinline__ float flog2(float x) { return __builtin_amdgcn_logf(x); }
__device__ __forceinline__ float rdlane63(float v) {
    return __uint_as_float(__builtin_amdgcn_readlane(__float_as_uint(v), 63));
}
__device__ __forceinline__ float bperm(int byteaddr, float v) {
    return __int_as_float(__builtin_amdgcn_ds_bpermute(byteaddr, __float_as_int(v)));
}

__global__ __launch_bounds__(256) void ctc_fwd(const int* __restrict__ y_true,
                                               const float* __restrict__ y_pred,
                                               float* __restrict__ out) {
    const int w    = blockIdx.x * 4 + (threadIdx.x >> 6);   // batch item
    const int lane = threadIdx.x & 63;

    // extended-label symbol for this lane's state
    int sym = BLANK;
    if (lane & 1) sym = y_true[w * Ll + (lane >> 1)];
    const int  sym2 = __shfl_up(sym, 2);
    const bool skip = (lane & 1) && (lane >= 3) && (sym != sym2);
    // fixed redistribution: column sym lives in lane sym>>1, element sym&1
    const int  srcaddr = (sym >> 1) << 2;   // bpermute byte address
    const bool oddcol  = (sym & 1) != 0;

    const float2* rowp =
        reinterpret_cast<const float2*>(y_pred + (size_t)w * Tt * Vv) + lane;

    // t = 0 init: only states 0,1 reachable (single scalar gather, one-off)
    const float lp0 = flog2(y_pred[(size_t)w * Tt * Vv + sym] + EPSF);
    float m   = (lane <= 1) ? lp0 : NEGF;
    float p   = 1.0f;
    float m64 = NEGF, p64 = 1.0f;     // state 64 (meaningful on lane 0)

    auto redistribute = [&](float2 r) -> float {
        const float c0 = bperm(srcaddr, r.x);
        const float c1 = bperm(srcaddr, r.y);
        return oddcol ? c1 : c0;
    };

    auto step = [&](float prob) {
        const float lp2 = flog2(prob + EPSF);            // off-chain
        const float m1  = __shfl_up(m, 1);
        const float m2s = __shfl_up(m, 2);
        const float p1  = __shfl_up(p, 1);
        const float p2  = __shfl_up(p, 2);
        const float m63 = rdlane63(m);                   // pre-update
        const float p63 = rdlane63(p);
        const float m1g = (lane >= 1) ? m1 : NEGF;
        const float m2g = skip ? m2s : NEGF;
        // states 0..63
        const float hi  = fmaxf(fmaxf(m, m1g), m2g);     // -> v_max3
        const float pn  = p  * fexp2(m   - hi)
                        + p1 * fexp2(m1g - hi)
                        + p2 * fexp2(m2g - hi);          // dead terms weigh 0
        // state 64: from {64, 63}, lp is lane 0's blank lp2
        const float hi2  = fmaxf(m64, m63);
        const float pn64 = p64 * fexp2(m64 - hi2) + p63 * fexp2(m63 - hi2);
        m   = hi  + lp2;  p   = pn;
        m64 = hi2 + lp2;  p64 = pn64;
    };
    auto renorm = [&]() {   // p <= 3^8 between renorms, fp32-safe
        m   += flog2(fmaxf(p,   1e-30f));  p   = 1.0f;
        m64 += flog2(fmaxf(p64, 1e-30f));  p64 = 1.0f;
    };

    // software-pipelined coalesced-load ring over t = 1..255
    float2 buf[PF];
#pragma unroll
    for (int i = 0; i < PF; ++i) buf[i] = rowp[(size_t)(1 + i) * (Vv / 2)];

    for (int tb = 1; tb + PF <= Tt; tb += PF) {   // t = 1..240
#pragma unroll
        for (int i = 0; i < PF; ++i) {
            const float2 r  = buf[i];
            const int    tn = tb + i + PF;
            if (tn < Tt) buf[i] = rowp[(size_t)tn * (Vv / 2)];
            step(redistribute(r));
            if ((i & 7) == 7) renorm();
        }
    }
#pragma unroll
    for (int i = 0; i < PF - 1; ++i) {            // t = 241..255
        step(redistribute(buf[i]));
        if (i == 7) renorm();
    }

    // loss = -ln2 * logaddexp2(alpha2[63], alpha2[64])
    const float a63 = rdlane63(m + flog2(fmaxf(p, 1e-30f)));
    if (lane == 0) {
        const float a64 = m64 + flog2(fmaxf(p64, 1e-30f));
        const float h = fmaxf(a63, a64);
        const float r = h + flog2(fexp2(a63 - h) + fexp2(a64 - h));
        out[w] = -r * LN2F;
    }
}

extern "C" void kernel_launch(void* const* d_in, const int* in_sizes, int n_in,
                              void* d_out, int out_size, void* d_ws, size_t ws_size,
                              hipStream_t stream) {
    const int*   y_true = (const int*)d_in[0];
    const float* y_pred = (const float*)d_in[1];
    float*       out    = (float*)d_out;
    ctc_fwd<<<dim3(Bb / 4), dim3(256), 0, stream>>>(y_true, y_pred, out);
}

// Round 6
// 52.914 us; speedup vs baseline: 1.0370x; 1.0370x over previous
//
#include <hip/hip_runtime.h>

// CTC batch loss forward (Keras ctc_batch_cost semantics).
// B=2048, T=256, L=32, V=128, blank=V-1=127, S=2L+1=65.
// One wave64 per batch item: lane s owns state s (0..63); lane 0 also owns
// state 64 (final blank, shares lane 0's blank log-prob).
// alpha in streaming-softmax form: alpha2 = m + log2(p) (base-2);
// m-recurrence = shfl -> max3 -> add (no transcendental on the chain),
// p folded into m every 8 steps.
// Memory: direct per-lane column gather (R4 structure — R5 proved coalescing
// doesn't help: full row fetched either way), PF=32 ring, branchless
// clamped prefetch so vmem issue is an unbroken clusterable stream.

constexpr int Bb = 2048;
constexpr int Tt = 256;
constexpr int Ll = 32;
constexpr int Vv = 128;
constexpr int BLANK = Vv - 1;
constexpr int PF = 32;
#define EPSF 1e-7f
#define NEGF -1e30f
#define LN2F 0.6931471805599453f

__device__ __forceinline__ float fexp2(float x) { return __builtin_amdgcn_exp2f(x); }
__device__ __forceinline__ float flog2(float x) { return __builtin_amdgcn_logf(x); }
__device__ __forceinline__ float rdlane63(float v) {
    return __uint_as_float(__builtin_amdgcn_readlane(__float_as_uint(v), 63));
}

__global__ __launch_bounds__(256) void ctc_fwd(const int* __restrict__ y_true,
                                               const float* __restrict__ y_pred,
                                               float* __restrict__ out) {
    const int w    = blockIdx.x * 4 + (threadIdx.x >> 6);   // batch item
    const int lane = threadIdx.x & 63;

    // extended-label symbol for this lane's state
    int sym = BLANK;
    if (lane & 1) sym = y_true[w * Ll + (lane >> 1)];
    const int  sym2 = __shfl_up(sym, 2);
    const bool skip = (lane & 1) && (lane >= 3) && (sym != sym2);

    const float* rp = y_pred + (size_t)w * Tt * Vv + sym;

    // t = 0 init: only states 0,1 reachable
    const float lp0 = flog2(rp[0] + EPSF);
    float m   = (lane <= 1) ? lp0 : NEGF;
    float p   = 1.0f;
    float m64 = NEGF, p64 = 1.0f;     // state 64 (meaningful on lane 0)

    auto step = [&](float prob) {
        const float lp2 = flog2(prob + EPSF);            // off-chain
        const float m1  = __shfl_up(m, 1);
        const float m2s = __shfl_up(m, 2);
        const float p1  = __shfl_up(p, 1);
        const float p2  = __shfl_up(p, 2);
        const float m63 = rdlane63(m);                   // pre-update
        const float p63 = rdlane63(p);
        const float m1g = (lane >= 1) ? m1 : NEGF;
        const float m2g = skip ? m2s : NEGF;
        // states 0..63
        const float hi  = fmaxf(fmaxf(m, m1g), m2g);     // -> v_max3
        const float pn  = p  * fexp2(m   - hi)
                        + p1 * fexp2(m1g - hi)
                        + p2 * fexp2(m2g - hi);          // dead terms weigh 0
        // state 64: from {64, 63}, lp is lane 0's blank lp2
        const float hi2  = fmaxf(m64, m63);
        const float pn64 = p64 * fexp2(m64 - hi2) + p63 * fexp2(m63 - hi2);
        m   = hi  + lp2;  p   = pn;
        m64 = hi2 + lp2;  p64 = pn64;
    };
    auto renorm = [&]() {   // p <= 3^8 between renorms, fp32-safe
        m   += flog2(fmaxf(p,   1e-30f));  p   = 1.0f;
        m64 += flog2(fmaxf(p64, 1e-30f));  p64 = 1.0f;
    };

    // software-pipelined gather ring over t = 1..255, PF = 32
    float buf[PF];
#pragma unroll
    for (int i = 0; i < PF; ++i) buf[i] = rp[(size_t)(1 + i) * Vv];

    // main: tb = 1, 33, ..., 193  (t = 1..224); slot for t is (t-1)&31 == i here
    for (int tb = 1; tb + PF <= Tt; tb += PF) {
#pragma unroll
        for (int i = 0; i < PF; ++i) {
            const float pr = buf[i];
            const int   tn = min(tb + i + PF, Tt - 1);   // branchless clamp
            buf[i] = rp[(size_t)tn * Vv];                // unconditional issue
            step(pr);
            if ((i & 7) == 7) renorm();
        }
    }
    // tail: t = 225..255 (31 steps), already resident in slots 0..30
#pragma unroll
    for (int i = 0; i < PF - 1; ++i) {
        step(buf[i]);
        if ((i & 7) == 7) renorm();
    }

    // loss = -ln2 * logaddexp2(alpha2[63], alpha2[64])
    const float a63 = rdlane63(m + flog2(fmaxf(p, 1e-30f)));
    if (lane == 0) {
        const float a64 = m64 + flog2(fmaxf(p64, 1e-30f));
        const float h = fmaxf(a63, a64);
        const float r = h + flog2(fexp2(a63 - h) + fexp2(a64 - h));
        out[w] = -r * LN2F;
    }
}

extern "C" void kernel_launch(void* const* d_in, const int* in_sizes, int n_in,
                              void* d_out, int out_size, void* d_ws, size_t ws_size,
                              hipStream_t stream) {
    const int*   y_true = (const int*)d_in[0];
    const float* y_pred = (const float*)d_in[1];
    float*       out    = (float*)d_out;
    ctc_fwd<<<dim3(Bb / 4), dim3(256), 0, stream>>>(y_true, y_pred, out);
}

// Round 7
// 47.656 us; speedup vs baseline: 1.1515x; 1.1103x over previous
//
#include <hip/hip_runtime.h>

// CTC batch loss forward (Keras ctc_batch_cost semantics).
// B=2048, T=256, L=32, V=128, blank=V-1=127, S=2L+1=65.
// One wave64 per batch item. State remap: lane l owns extended state l+1
// (even lane -> label l/2, odd lane -> blank; lane 63 -> final blank state 64).
// State 0 (first blank, self-loop only) is a uniform running sum b0.
// alpha in streaming-softmax form: alpha2 = m + log2(p) (base-2);
// cross-lane moves via DPP wave_shr:1 (VALU pipe, no DS ops on the chain);
// renorm folds p into m every 8 steps.
// Memory: R4's direct per-lane column gather, PF=16 ring (proved best).

constexpr int Bb = 2048;
constexpr int Tt = 256;
constexpr int Ll = 32;
constexpr int Vv = 128;
constexpr int BLANK = Vv - 1;
constexpr int PF = 16;
#define EPSF 1e-7f
#define NEGF -1e30f
#define LN2F 0.6931471805599453f

__device__ __forceinline__ float fexp2(float x) { return __builtin_amdgcn_exp2f(x); }
__device__ __forceinline__ float flog2(float x) { return __builtin_amdgcn_logf(x); }
__device__ __forceinline__ float rdlane(float v, int l) {
    return __uint_as_float(__builtin_amdgcn_readlane(__float_as_uint(v), l));
}
// whole-wave shift-up-by-1 in the VALU pipe; lane 0 receives `old`
__device__ __forceinline__ float dpp_shr1(float old, float src) {
    return __int_as_float(__builtin_amdgcn_update_dpp(
        __float_as_int(old), __float_as_int(src), 0x138 /*WAVE_SHR1*/,
        0xf, 0xf, false));
}

__global__ __launch_bounds__(256) void ctc_fwd(const int* __restrict__ y_true,
                                               const float* __restrict__ y_pred,
                                               float* __restrict__ out) {
    const int w    = blockIdx.x * 4 + (threadIdx.x >> 6);   // batch item
    const int lane = threadIdx.x & 63;

    // lane l owns state l+1: even lane -> label l/2, odd lane -> blank
    int sym = BLANK;
    if (!(lane & 1)) sym = y_true[w * Ll + (lane >> 1)];
    const int  symm2 = __shfl_up(sym, 2);                 // init-time only
    const bool skip  = !(lane & 1) && (lane >= 2) && (sym != symm2);

    const float* rp = y_pred + (size_t)w * Tt * Vv + sym;

    // t = 0: alpha[0] = blank lp (-> b0), alpha[1] = label0 lp (lane 0)
    const float lp20 = flog2(rp[0] + EPSF);
    float b0 = rdlane(lp20, 1);                           // blank column lp at t0
    float m  = (lane == 0) ? lp20 : NEGF;
    float p  = 1.0f;
    const float negv = NEGF;
    const float onev = 1.0f;

    auto step = [&](float prob) {
        const float lp2  = flog2(prob + EPSF);            // off-chain
        const float lpb  = rdlane(lp2, 1);                // blank lp (uniform)
        const float b0p  = b0;
        // s-1 inputs: lane0 <- state 0 = (b0, 1)
        const float m1g = dpp_shr1(b0p,  m);
        const float p1g = dpp_shr1(onev, p);
        // s-2 inputs: chain another shr1 (lane0 <- NEG, lane1 <- state 0)
        const float m2s = dpp_shr1(negv, m1g);
        const float p2g = dpp_shr1(onev, p1g);
        const float m2g = skip ? m2s : NEGF;
        const float hi  = fmaxf(fmaxf(m, m1g), m2g);      // -> v_max3
        const float pn  = p   * fexp2(m   - hi)
                        + p1g * fexp2(m1g - hi)
                        + p2g * fexp2(m2g - hi);          // dead terms weigh 0
        m  = hi + lp2;
        p  = pn;
        b0 = b0p + lpb;                                   // state 0 self-loop
    };
    auto renorm = [&]() {   // p <= 3^8 between renorms, fp32-safe
        m += flog2(fmaxf(p, 1e-30f));  p = 1.0f;
    };

    // software-pipelined gather ring over t = 1..255 (R4 structure)
    float buf[PF];
#pragma unroll
    for (int i = 0; i < PF; ++i) buf[i] = rp[(size_t)(1 + i) * Vv];

    for (int tb = 1; tb + PF <= Tt; tb += PF) {   // t = 1..240
#pragma unroll
        for (int i = 0; i < PF; ++i) {
            const float pr = buf[i];
            const int   tn = tb + i + PF;
            if (tn < Tt) buf[i] = rp[(size_t)tn * Vv];
            step(pr);
            if ((i & 7) == 7) renorm();
        }
    }
#pragma unroll
    for (int i = 0; i < PF - 1; ++i) {            // t = 241..255
        step(buf[i]);
        if (i == 7) renorm();
    }

    // loss = -ln2 * logaddexp2(alpha2[63](=lane62), alpha2[64](=lane63))
    const float afin = m + flog2(fmaxf(p, 1e-30f));
    const float aA = rdlane(afin, 62);
    const float aB = rdlane(afin, 63);
    if (lane == 0) {
        const float h = fmaxf(aA, aB);
        const float r = h + flog2(fexp2(aA - h) + fexp2(aB - h));
        out[w] = -r * LN2F;
    }
}

extern "C" void kernel_launch(void* const* d_in, const int* in_sizes, int n_in,
                              void* d_out, int out_size, void* d_ws, size_t ws_size,
                              hipStream_t stream) {
    const int*   y_true = (const int*)d_in[0];
    const float* y_pred = (const float*)d_in[1];
    float*       out    = (float*)d_out;
    ctc_fwd<<<dim3(Bb / 4), dim3(256), 0, stream>>>(y_true, y_pred, out);
}

// Round 8
// 46.662 us; speedup vs baseline: 1.1760x; 1.0213x over previous
//
#include <hip/hip_runtime.h>

// CTC batch loss forward (Keras ctc_batch_cost semantics).
// B=2048, T=256, L=32, V=128, blank=V-1=127, S=2L+1=65.
// Producer/consumer wave split per batch item (block = 128 threads):
//   wave 0 (producer): gathers y_pred[b][t][sym_lane] per row, computes
//     lp2 = log2(p+eps), writes to LDS ring (2 x 16 rows x 64 lanes).
//   wave 1 (consumer): pure-register CTC DP. Lane l owns extended state
//     l+1 (even lane -> label l/2, odd lane -> blank; lane 63 -> state 64).
//     State 0 (first blank, self-loop) is a uniform running sum b0.
//     alpha2 = m + log2(p) streaming-softmax form; cross-lane via DPP
//     wave_shr:1 (VALU pipe); p folded into m every 8 steps.
// One __syncthreads per 16-row chunk (16 total), double-buffered.

constexpr int Bb = 2048;
constexpr int Tt = 256;
constexpr int Ll = 32;
constexpr int Vv = 128;
constexpr int BLANK = Vv - 1;
constexpr int CHUNK = 16;
constexpr int NCH = Tt / CHUNK;     // 16
#define EPSF 1e-7f
#define NEGF -1e30f
#define LN2F 0.6931471805599453f

__device__ __forceinline__ float fexp2(float x) { return __builtin_amdgcn_exp2f(x); }
__device__ __forceinline__ float flog2(float x) { return __builtin_amdgcn_logf(x); }
__device__ __forceinline__ float rdlane(float v, int l) {
    return __uint_as_float(__builtin_amdgcn_readlane(__float_as_uint(v), l));
}
// whole-wave shift-up-by-1 in the VALU pipe; lane 0 receives `old`
__device__ __forceinline__ float dpp_shr1(float old, float src) {
    return __int_as_float(__builtin_amdgcn_update_dpp(
        __float_as_int(old), __float_as_int(src), 0x138 /*WAVE_SHR1*/,
        0xf, 0xf, false));
}

__global__ __launch_bounds__(128) void ctc_fwd(const int* __restrict__ y_true,
                                               const float* __restrict__ y_pred,
                                               float* __restrict__ out) {
    const int w    = blockIdx.x;            // batch item
    const int wave = threadIdx.x >> 6;      // 0 = producer, 1 = consumer
    const int lane = threadIdx.x & 63;

    __shared__ float buf[2][CHUNK][64];     // lp2 ring, 8 KB

    // lane l owns state l+1: even lane -> label l/2, odd lane -> blank
    int sym = BLANK;
    if (!(lane & 1)) sym = y_true[w * Ll + (lane >> 1)];

    if (wave == 0) {
        // ---------------- producer ----------------
        const float* rp = y_pred + (size_t)w * Tt * Vv + sym;
        float rA[CHUNK], rB[CHUNK];
#pragma unroll
        for (int i = 0; i < CHUNK; ++i) rA[i] = rp[(size_t)i * Vv];
        for (int cc = 0; cc < NCH / 2; ++cc) {
            const int c0 = 2 * cc, c1 = 2 * cc + 1;
            // phase A: consume rA -> buf[0]; issue chunk c1 into rB
#pragma unroll
            for (int i = 0; i < CHUNK; ++i)
                rB[i] = rp[(size_t)(c1 * CHUNK + i) * Vv];
#pragma unroll
            for (int i = 0; i < CHUNK; ++i)
                buf[0][i][lane] = flog2(rA[i] + EPSF);
            __syncthreads();
            // phase B: consume rB -> buf[1]; issue chunk c1+1 into rA
            if (c1 + 1 < NCH) {
#pragma unroll
                for (int i = 0; i < CHUNK; ++i)
                    rA[i] = rp[(size_t)((c1 + 1) * CHUNK + i) * Vv];
            }
#pragma unroll
            for (int i = 0; i < CHUNK; ++i)
                buf[1][i][lane] = flog2(rB[i] + EPSF);
            __syncthreads();
        }
    } else {
        // ---------------- consumer ----------------
        const int  symm2 = __shfl_up(sym, 2);
        const bool skip  = !(lane & 1) && (lane >= 2) && (sym != symm2);

        float m = NEGF, p = 1.0f, b0 = 0.0f;

        auto step = [&](float lp2) {
            const float lpb = rdlane(lp2, 1);        // blank lp (uniform)
            const float b0p = b0;
            const float m1g = dpp_shr1(b0p,  m);     // s-1 (lane0 <- state 0)
            const float p1g = dpp_shr1(1.0f, p);
            const float m2s = dpp_shr1(NEGF, m1g);   // s-2
            const float p2g = dpp_shr1(1.0f, p1g);
            const float m2g = skip ? m2s : NEGF;
            const float hi  = fmaxf(fmaxf(m, m1g), m2g);   // -> v_max3
            const float pn  = p   * fexp2(m   - hi)
                            + p1g * fexp2(m1g - hi)
                            + p2g * fexp2(m2g - hi);       // dead terms weigh 0
            m  = hi + lp2;
            p  = pn;
            b0 = b0p + lpb;                          // state 0 self-loop
        };
        auto renorm = [&]() {   // p <= 3^8 between renorms, fp32-safe
            m += flog2(fmaxf(p, 1e-30f));  p = 1.0f;
        };

        for (int c = 0; c < NCH; ++c) {
            __syncthreads();                         // chunk c data ready
            float lp[CHUNK];
#pragma unroll
            for (int i = 0; i < CHUNK; ++i) lp[i] = buf[c & 1][i][lane];
            if (c == 0) {
                // t=0 init: alpha[1] on lane 0; b0 = blank lp (lane 1's value)
                b0 = rdlane(lp[0], 1);
                m  = (lane == 0) ? lp[0] : NEGF;
                p  = 1.0f;
#pragma unroll
                for (int i = 1; i < CHUNK; ++i) {
                    step(lp[i]);
                    if ((i & 7) == 7) renorm();
                }
            } else {
#pragma unroll
                for (int i = 0; i < CHUNK; ++i) {
                    step(lp[i]);
                    if ((i & 7) == 7) renorm();
                }
            }
        }

        // loss = -ln2 * logaddexp2(alpha2[63](=lane62), alpha2[64](=lane63))
        const float afin = m + flog2(fmaxf(p, 1e-30f));
        const float aA = rdlane(afin, 62);
        const float aB = rdlane(afin, 63);
        if (lane == 0) {
            const float h = fmaxf(aA, aB);
            const float r = h + flog2(fexp2(aA - h) + fexp2(aB - h));
            out[w] = -r * LN2F;
        }
    }
}

extern "C" void kernel_launch(void* const* d_in, const int* in_sizes, int n_in,
                              void* d_out, int out_size, void* d_ws, size_t ws_size,
                              hipStream_t stream) {
    const int*   y_true = (const int*)d_in[0];
    const float* y_pred = (const float*)d_in[1];
    float*       out    = (float*)d_out;
    ctc_fwd<<<dim3(Bb), dim3(128), 0, stream>>>(y_true, y_pred, out);
}